// Round 1
// baseline (397.164 us; speedup 1.0000x reference)
//
#include <hip/hip_runtime.h>
#include <hip/hip_bf16.h>

#define EMB   1024
#define SEQ   2048
#define BATCH 4
#define NH    16
#define DHEAD 64
#define MROWS (BATCH*SEQ)   // 8192

typedef float f32x4 __attribute__((ext_vector_type(4)));
typedef short s16x8 __attribute__((ext_vector_type(8)));

__device__ __forceinline__ f32x4 mfma16(s16x8 a, s16x8 b, f32x4 c) {
    return __builtin_amdgcn_mfma_f32_16x16x32_bf16(a, b, c, 0, 0, 0);
}

__device__ __forceinline__ unsigned short f2bf(float f) {
    __hip_bfloat16 h = __float2bfloat16(f);
    return __builtin_bit_cast(unsigned short, h);
}

// ---------------- fp32 -> bf16 conversion (vectorized) ----------------
__global__ void cvt_bf16(const float* __restrict__ in, unsigned short* __restrict__ out, int n4) {
    int i = blockIdx.x * blockDim.x + threadIdx.x;
    if (i >= n4) return;
    float4 v = reinterpret_cast<const float4*>(in)[i];
    ushort4 o;
    o.x = f2bf(v.x); o.y = f2bf(v.y); o.z = f2bf(v.z); o.w = f2bf(v.w);
    reinterpret_cast<ushort4*>(out)[i] = o;
}

// ---------------- bf16 GEMM: C[M,N] = A[M,K] * B[N,K]^T + bias ----------------
// EPI==0: write bf16 to head-split [B,H,S,Dh] buffer.  EPI==1: write fp32 row-major + bias.
#define GLDS(g, s) __builtin_amdgcn_global_load_lds((const __attribute__((address_space(1))) void*)(g), \
                       (__attribute__((address_space(3))) void*)(s), 16, 0, 0)

template<int EPI>
__global__ __launch_bounds__(256) void gemm_bt(const unsigned short* __restrict__ A,
                                               const unsigned short* __restrict__ Bw,
                                               const float* __restrict__ bias,
                                               void* __restrict__ Out) {
    __shared__ unsigned short sA[128*32];
    __shared__ unsigned short sB[128*32];
    const int tid = threadIdx.x;
    const int w  = tid >> 6, l = tid & 63;
    const int lg = l >> 4,  lr = l & 15;
    const int mBase = blockIdx.y * 128;
    const int nBase = blockIdx.x * 128;
    const int wr = w >> 1, wc = w & 1;
    const int srow = l >> 2;           // row within a 16-row staging chunk
    const int sk0  = (l & 3) * 8;      // k offset within row

    f32x4 acc[4][4] = {};

    for (int kb = 0; kb < EMB; kb += 32) {
        __syncthreads();
        #pragma unroll
        for (int rr = 0; rr < 2; ++rr) {
            const int chunk = w + rr * 4;                 // wave-uniform
            const unsigned short* ga = A  + (size_t)(mBase + chunk*16 + srow) * EMB + kb + sk0;
            GLDS(ga, &sA[chunk * 512]);
            const unsigned short* gb = Bw + (size_t)(nBase + chunk*16 + srow) * EMB + kb + sk0;
            GLDS(gb, &sB[chunk * 512]);
        }
        __syncthreads();
        s16x8 af[4], bf[4];
        #pragma unroll
        for (int mi = 0; mi < 4; ++mi)
            af[mi] = *reinterpret_cast<const s16x8*>(&sA[(wr*64 + mi*16 + lr)*32 + lg*8]);
        #pragma unroll
        for (int ni = 0; ni < 4; ++ni)
            bf[ni] = *reinterpret_cast<const s16x8*>(&sB[(wc*64 + ni*16 + lr)*32 + lg*8]);
        #pragma unroll
        for (int mi = 0; mi < 4; ++mi)
            #pragma unroll
            for (int ni = 0; ni < 4; ++ni)
                acc[mi][ni] = mfma16(af[mi], bf[ni], acc[mi][ni]);
    }

    const int colBase = nBase + wc * 64;
    const int rowBase = mBase + wr * 64;
    if (EPI == 0) {
        unsigned short* outp = (unsigned short*)Out;
        #pragma unroll
        for (int ni = 0; ni < 4; ++ni) {
            const int col = colBase + ni*16 + lr;
            const float bv = bias[col];
            const int h = col >> 6, d = col & 63;
            #pragma unroll
            for (int mi = 0; mi < 4; ++mi) {
                #pragma unroll
                for (int r = 0; r < 4; ++r) {
                    const int gr = rowBase + mi*16 + lg*4 + r;
                    const int b = gr >> 11, s = gr & 2047;
                    outp[((size_t)(b*NH + h) * SEQ + s) * DHEAD + d] = f2bf(acc[mi][ni][r] + bv);
                }
            }
        }
    } else {
        float* outp = (float*)Out;
        #pragma unroll
        for (int ni = 0; ni < 4; ++ni) {
            const int col = colBase + ni*16 + lr;
            const float bv = bias[col];
            #pragma unroll
            for (int mi = 0; mi < 4; ++mi) {
                #pragma unroll
                for (int r = 0; r < 4; ++r) {
                    const int gr = rowBase + mi*16 + lg*4 + r;
                    outp[(size_t)gr * EMB + col] = acc[mi][ni][r] + bv;
                }
            }
        }
    }
}

// ---------------- flash attention (causal), bf16 MFMA ----------------
// grid: (SEQ/64, BATCH*NH), block 256.  Each block: one (b,h), 64 Q rows.
// 4 waves, each owns a 16-row Q strip.  KV tiles of 64.
__global__ __launch_bounds__(256) void attn_fwd(const unsigned short* __restrict__ qb,
                                                const unsigned short* __restrict__ kb,
                                                const unsigned short* __restrict__ vb,
                                                unsigned short* __restrict__ ctx) {
    __shared__ unsigned short sk[64 * 72];   // K tile, row-major [kv][d], stride 72
    __shared__ unsigned short svt[64 * 72];  // V tile transposed [d][kv], stride 72
    __shared__ unsigned short sp[4 * 16 * 72]; // per-wave P strips

    const int tid = threadIdx.x;
    const int w  = tid >> 6, l = tid & 63;
    const int lg = l >> 4,  lr = l & 15;
    const int qt = (int)gridDim.x - 1 - (int)blockIdx.x;  // heavy tiles dispatch first
    const int bh = blockIdx.y;
    const size_t hb = (size_t)bh * SEQ * DHEAD;
    const unsigned short* qh = qb + hb;
    const unsigned short* kh = kb + hb;
    const unsigned short* vh = vb + hb;
    const int r0 = w * 16;

    // Q fragments (A-operand): row = lr of strip, k = d
    const size_t qoff = (size_t)(qt*64 + r0 + lr) * DHEAD + lg * 8;
    const s16x8 qf0 = *reinterpret_cast<const s16x8*>(&qh[qoff]);
    const s16x8 qf1 = *reinterpret_cast<const s16x8*>(&qh[qoff + 32]);

    f32x4 o[4] = {};
    float mrow[4], lsum[4];
    #pragma unroll
    for (int r = 0; r < 4; ++r) { mrow[r] = -__builtin_inff(); lsum[r] = 0.f; }

    const int skv = tid >> 2;        // 0..63 staging row
    const int sd  = (tid & 3) * 16;  // staging d offset

    unsigned short* spw = &sp[w * 16 * 72];

    for (int t = 0; t <= qt; ++t) {
        const int kvb = t * 64;
        __syncthreads();  // protect prev-iter LDS reads
        // ---- stage K (row-major) and V (transposed) ----
        {
            const size_t goff = (size_t)(kvb + skv) * DHEAD + sd;
            const s16x8 k0 = *reinterpret_cast<const s16x8*>(&kh[goff]);
            const s16x8 k1 = *reinterpret_cast<const s16x8*>(&kh[goff + 8]);
            const s16x8 v0 = *reinterpret_cast<const s16x8*>(&vh[goff]);
            const s16x8 v1 = *reinterpret_cast<const s16x8*>(&vh[goff + 8]);
            *reinterpret_cast<s16x8*>(&sk[skv*72 + sd])     = k0;
            *reinterpret_cast<s16x8*>(&sk[skv*72 + sd + 8]) = k1;
            #pragma unroll
            for (int j = 0; j < 8; ++j) {
                svt[(sd + j)     * 72 + skv] = (unsigned short)(unsigned)(unsigned short)v0[j];
                svt[(sd + 8 + j) * 72 + skv] = (unsigned short)(unsigned)(unsigned short)v1[j];
            }
        }
        __syncthreads();

        // ---- S = Q K^T (per wave: 16x64) ----
        f32x4 sfr[4] = {};
        #pragma unroll
        for (int nf = 0; nf < 4; ++nf) {
            const s16x8 b0 = *reinterpret_cast<const s16x8*>(&sk[(nf*16 + lr)*72 + lg*8]);
            const s16x8 b1 = *reinterpret_cast<const s16x8*>(&sk[(nf*16 + lr)*72 + 32 + lg*8]);
            sfr[nf] = mfma16(qf0, b0, sfr[nf]);
            sfr[nf] = mfma16(qf1, b1, sfr[nf]);
        }

        // ---- scale + causal mask + online softmax ----
        const bool diag = (t == qt);
        float pm[4];
        #pragma unroll
        for (int r = 0; r < 4; ++r) pm[r] = -__builtin_inff();
        #pragma unroll
        for (int nf = 0; nf < 4; ++nf) {
            #pragma unroll
            for (int r = 0; r < 4; ++r) {
                float sv = sfr[nf][r] * 0.125f;
                if (diag && (nf*16 + lr > r0 + lg*4 + r)) sv = -__builtin_inff();
                sfr[nf][r] = sv;
                pm[r] = fmaxf(pm[r], sv);
            }
        }
        float fs[4];
        #pragma unroll
        for (int r = 0; r < 4; ++r) {
            #pragma unroll
            for (int d = 1; d < 16; d <<= 1) pm[r] = fmaxf(pm[r], __shfl_xor(pm[r], d));
            const float mn = fmaxf(mrow[r], pm[r]);
            fs[r] = __expf(mrow[r] - mn);
            mrow[r] = mn;
        }
        float rs[4] = {0.f, 0.f, 0.f, 0.f};
        #pragma unroll
        for (int nf = 0; nf < 4; ++nf) {
            #pragma unroll
            for (int r = 0; r < 4; ++r) {
                const float p = __expf(sfr[nf][r] - mrow[r]);
                sfr[nf][r] = p;
                rs[r] += p;
            }
        }
        #pragma unroll
        for (int r = 0; r < 4; ++r) {
            #pragma unroll
            for (int d = 1; d < 16; d <<= 1) rs[r] += __shfl_xor(rs[r], d);
            lsum[r] = lsum[r] * fs[r] + rs[r];
        }
        #pragma unroll
        for (int nf = 0; nf < 4; ++nf)
            #pragma unroll
            for (int r = 0; r < 4; ++r) o[nf][r] *= fs[r];

        // ---- write P (bf16) to per-wave LDS, re-fragment as A-operand ----
        #pragma unroll
        for (int nf = 0; nf < 4; ++nf)
            #pragma unroll
            for (int r = 0; r < 4; ++r)
                spw[(lg*4 + r)*72 + nf*16 + lr] = f2bf(sfr[nf][r]);
        __syncthreads();

        const s16x8 pa0 = *reinterpret_cast<const s16x8*>(&spw[lr*72 + lg*8]);
        const s16x8 pa1 = *reinterpret_cast<const s16x8*>(&spw[lr*72 + 32 + lg*8]);
        #pragma unroll
        for (int nf = 0; nf < 4; ++nf) {
            const s16x8 vb0 = *reinterpret_cast<const s16x8*>(&svt[(nf*16 + lr)*72 + lg*8]);
            const s16x8 vb1 = *reinterpret_cast<const s16x8*>(&svt[(nf*16 + lr)*72 + 32 + lg*8]);
            o[nf] = mfma16(pa0, vb0, o[nf]);
            o[nf] = mfma16(pa1, vb1, o[nf]);
        }
    }

    // ---- epilogue: normalize and write ctx [B*S, E] bf16 ----
    const int b = bh >> 4, h = bh & 15;
    #pragma unroll
    for (int r = 0; r < 4; ++r) lsum[r] = 1.f / lsum[r];
    #pragma unroll
    for (int nf = 0; nf < 4; ++nf) {
        #pragma unroll
        for (int r = 0; r < 4; ++r) {
            const int srow = qt*64 + r0 + lg*4 + r;
            ctx[((size_t)(b*SEQ + srow)) * EMB + h*DHEAD + nf*16 + lr] = f2bf(o[nf][r] * lsum[r]);
        }
    }
}

// ---------------- launch ----------------
extern "C" void kernel_launch(void* const* d_in, const int* in_sizes, int n_in,
                              void* d_out, int out_size, void* d_ws, size_t ws_size,
                              hipStream_t stream) {
    const float* x  = (const float*)d_in[0];
    const float* wq = (const float*)d_in[1];
    const float* bq = (const float*)d_in[2];
    const float* wk = (const float*)d_in[3];
    const float* bk = (const float*)d_in[4];
    const float* wv = (const float*)d_in[5];
    const float* bv = (const float*)d_in[6];
    const float* wo = (const float*)d_in[7];
    const float* bo = (const float*)d_in[8];
    float* out = (float*)d_out;

    char* ws = (char*)d_ws;
    const size_t MB = 1ull << 20;
    unsigned short* xb  = (unsigned short*)(ws);            // 16 MB; reused as ctx later
    unsigned short* wqb = (unsigned short*)(ws + 16*MB);
    unsigned short* wkb = (unsigned short*)(ws + 18*MB);
    unsigned short* wvb = (unsigned short*)(ws + 20*MB);
    unsigned short* wob = (unsigned short*)(ws + 22*MB);
    unsigned short* qB  = (unsigned short*)(ws + 24*MB);
    unsigned short* kB  = (unsigned short*)(ws + 40*MB);
    unsigned short* vB  = (unsigned short*)(ws + 56*MB);
    unsigned short* ctx = xb;  // x-bf16 dead after QKV GEMMs

    const int nx4 = MROWS * EMB / 4;
    const int nw4 = EMB * EMB / 4;
    cvt_bf16<<<(nx4 + 255)/256, 256, 0, stream>>>(x,  xb,  nx4);
    cvt_bf16<<<(nw4 + 255)/256, 256, 0, stream>>>(wq, wqb, nw4);
    cvt_bf16<<<(nw4 + 255)/256, 256, 0, stream>>>(wk, wkb, nw4);
    cvt_bf16<<<(nw4 + 255)/256, 256, 0, stream>>>(wv, wvb, nw4);
    cvt_bf16<<<(nw4 + 255)/256, 256, 0, stream>>>(wo, wob, nw4);

    dim3 gg(EMB/128, MROWS/128);  // (8, 64)
    gemm_bt<0><<<gg, 256, 0, stream>>>(xb, wqb, bq, (void*)qB);
    gemm_bt<0><<<gg, 256, 0, stream>>>(xb, wkb, bk, (void*)kB);
    gemm_bt<0><<<gg, 256, 0, stream>>>(xb, wvb, bv, (void*)vB);

    dim3 ga(SEQ/64, BATCH*NH);    // (32, 64)
    attn_fwd<<<ga, 256, 0, stream>>>(qB, kB, vB, ctx);

    gemm_bt<1><<<gg, 256, 0, stream>>>(ctx, wob, bo, (void*)out);
}